// Round 3
// baseline (266.481 us; speedup 1.0000x reference)
//
#include <hip/hip_runtime.h>
#include <math.h>

#define N_NODES 50000
#define N_EDGES 800000
#define F_IN    128
#define F_OUT   64
#define ALPHA   0.2f

#define NP      50176              // N_NODES padded to 196*256
#define NB      196                // scan blocks

// ---------------------------------------------------------------------------
// K1: h = input @ W  (50000x128 @ 128x64), plus per-node attention scores
//     ssrc[i] = h[i,:] . a[0:64],  sdst[i] = h[i,:] . a[64:128]
// One wave computes 4 rows (lane = output column). W staged in LDS (32 KB).
// Wl read: lane i -> bank i%32, 2-way alias = free (m136).
// ---------------------------------------------------------------------------
__global__ __launch_bounds__(256) void k_gemm_scores(
    const float* __restrict__ in, const float* __restrict__ W,
    const float* __restrict__ a, float* __restrict__ h,
    float* __restrict__ ssrc, float* __restrict__ sdst) {
  __shared__ float Wl[F_IN * F_OUT];   // 32 KB, row-major [k][j]
  __shared__ float al[2 * F_OUT];

  for (int i = threadIdx.x; i < F_IN * F_OUT; i += 256) Wl[i] = W[i];
  if (threadIdx.x < 2 * F_OUT) al[threadIdx.x] = a[threadIdx.x];
  __syncthreads();

  const int wave = threadIdx.x >> 6;
  const int lane = threadIdx.x & 63;
  const int row0 = (blockIdx.x * 4 + wave) * 4;

  const float* rb = in + (size_t)row0 * F_IN;
  float acc0 = 0.f, acc1 = 0.f, acc2 = 0.f, acc3 = 0.f;

  #pragma unroll 8
  for (int k4 = 0; k4 < F_IN / 4; ++k4) {
    const float4 i0 = *reinterpret_cast<const float4*>(rb + 0 * F_IN + k4 * 4);
    const float4 i1 = *reinterpret_cast<const float4*>(rb + 1 * F_IN + k4 * 4);
    const float4 i2 = *reinterpret_cast<const float4*>(rb + 2 * F_IN + k4 * 4);
    const float4 i3 = *reinterpret_cast<const float4*>(rb + 3 * F_IN + k4 * 4);
    #pragma unroll
    for (int j = 0; j < 4; ++j) {
      const float w = Wl[(k4 * 4 + j) * F_OUT + lane];
      acc0 += (&i0.x)[j] * w;
      acc1 += (&i1.x)[j] * w;
      acc2 += (&i2.x)[j] * w;
      acc3 += (&i3.x)[j] * w;
    }
  }

  h[(size_t)(row0 + 0) * F_OUT + lane] = acc0;
  h[(size_t)(row0 + 1) * F_OUT + lane] = acc1;
  h[(size_t)(row0 + 2) * F_OUT + lane] = acc2;
  h[(size_t)(row0 + 3) * F_OUT + lane] = acc3;

  const float as = al[lane], ad = al[F_OUT + lane];
  float ts0 = acc0 * as, td0 = acc0 * ad;
  float ts1 = acc1 * as, td1 = acc1 * ad;
  float ts2 = acc2 * as, td2 = acc2 * ad;
  float ts3 = acc3 * as, td3 = acc3 * ad;
  #pragma unroll
  for (int off = 32; off; off >>= 1) {
    ts0 += __shfl_xor(ts0, off); td0 += __shfl_xor(td0, off);
    ts1 += __shfl_xor(ts1, off); td1 += __shfl_xor(td1, off);
    ts2 += __shfl_xor(ts2, off); td2 += __shfl_xor(td2, off);
    ts3 += __shfl_xor(ts3, off); td3 += __shfl_xor(td3, off);
  }
  if (lane == 0) {
    ssrc[row0 + 0] = ts0; sdst[row0 + 0] = td0;
    ssrc[row0 + 1] = ts1; sdst[row0 + 1] = td1;
    ssrc[row0 + 2] = ts2; sdst[row0 + 2] = td2;
    ssrc[row0 + 3] = ts3; sdst[row0 + 3] = td3;
  }
}

// ---------------------------------------------------------------------------
// CSR build: histogram of src, 2-level exclusive scan, scatter {dst, ee}.
// ---------------------------------------------------------------------------
__global__ __launch_bounds__(256) void k_hist(const int* __restrict__ src,
                                              int* __restrict__ deg) {
  const int e = blockIdx.x * 256 + threadIdx.x;   // grid exact: 800000
  atomicAdd(&deg[src[e]], 1);
}

// per-block exclusive scan of 256 elements; bsum[b] = block total
__global__ __launch_bounds__(256) void k_scan_a(const int* __restrict__ deg,
                                                int* __restrict__ offs,
                                                int* __restrict__ bsum) {
  __shared__ int lds[256];
  const int i = blockIdx.x * 256 + threadIdx.x;   // deg zero-padded to NP
  const int v = deg[i];
  lds[threadIdx.x] = v;
  __syncthreads();
  #pragma unroll
  for (int off = 1; off < 256; off <<= 1) {
    int t = (threadIdx.x >= off) ? lds[threadIdx.x - off] : 0;
    __syncthreads();
    lds[threadIdx.x] += t;
    __syncthreads();
  }
  offs[i] = lds[threadIdx.x] - v;                 // exclusive within block
  if (threadIdx.x == 255) bsum[blockIdx.x] = lds[255];
}

// exclusive scan of the NB block sums (single block). bsum[NB..255] is
// POISON (0xAA) — guard the load.
__global__ __launch_bounds__(256) void k_scan_b(const int* __restrict__ bsum,
                                                int* __restrict__ boff) {
  __shared__ int lds[256];
  const int v = (threadIdx.x < NB) ? bsum[threadIdx.x] : 0;
  lds[threadIdx.x] = v;
  __syncthreads();
  #pragma unroll
  for (int off = 1; off < 256; off <<= 1) {
    int t = (threadIdx.x >= off) ? lds[threadIdx.x - off] : 0;
    __syncthreads();
    lds[threadIdx.x] += t;
    __syncthreads();
  }
  boff[threadIdx.x] = lds[threadIdx.x] - v;
}

// one thread per edge: compute ee once, place {dst, ee} in CSR slot of src
__global__ __launch_bounds__(256) void k_scatter(
    const int* __restrict__ src, const int* __restrict__ dst,
    const float* __restrict__ adj,
    const float* __restrict__ ssrc, const float* __restrict__ sdst,
    const int* __restrict__ offs, const int* __restrict__ boff,
    int* __restrict__ cursor, int2* __restrict__ pairs) {
  const int e = blockIdx.x * 256 + threadIdx.x;   // grid exact: 800000
  const int s = src[e];
  const int d = dst[e];
  const float sc = ssrc[s] + sdst[d];
  const float lr = sc > 0.f ? sc : ALPHA * sc;
  const float ee = expf(-lr) * adj[e];
  const int base = offs[s] + boff[s >> 8];
  const int pos  = base + atomicAdd(&cursor[s], 1);
  pairs[pos] = make_int2(d, __float_as_int(ee));
}

// ---------------------------------------------------------------------------
// K4: per-node gather + divide + ELU (fused epilogue). Wave per node,
// lane = feature. 2-edge unrolled: both pair loads + both h-row loads are
// issued before the FMAs -> 2x memory-level parallelism (the un-unrolled
// chain pairs[j] -> h[dst] row sustains only ~10 TB/s chip-wide at ~500cy
// L3 latency; this was the modeled latency leak).
// ---------------------------------------------------------------------------
__global__ __launch_bounds__(256) void k_gather(
    const int2* __restrict__ pairs, const int* __restrict__ offs,
    const int* __restrict__ boff, const float* __restrict__ h,
    float* __restrict__ out) {
  const int wave = threadIdx.x >> 6;
  const int lane = threadIdx.x & 63;
  const int node = blockIdx.x * 4 + wave;         // grid exact: 12500

  const int o0 = offs[node] + boff[node >> 8];
  const int o1 = offs[node + 1] + boff[(node + 1) >> 8];

  float acc = 0.f, rs = 0.f;
  int j = o0;
  for (; j + 1 < o1; j += 2) {
    const int2 p0 = pairs[j];
    const int2 p1 = pairs[j + 1];
    const float h0 = h[(size_t)p0.x * F_OUT + lane];
    const float h1 = h[(size_t)p1.x * F_OUT + lane];
    const float e0 = __int_as_float(p0.y);
    const float e1 = __int_as_float(p1.y);
    acc += e0 * h0; rs += e0;
    acc += e1 * h1; rs += e1;
  }
  if (j < o1) {
    const int2 p = pairs[j];
    const float ee = __int_as_float(p.y);
    acc += ee * h[(size_t)p.x * F_OUT + lane];
    rs  += ee;
  }

  float v = acc / rs;                             // deg==0 -> NaN, matches ref
  v = v > 0.f ? v : expm1f(v);
  out[(size_t)node * F_OUT + lane] = v;
}

extern "C" void kernel_launch(void* const* d_in, const int* in_sizes, int n_in,
                              void* d_out, int out_size, void* d_ws, size_t ws_size,
                              hipStream_t stream) {
  const float* input = (const float*)d_in[0];
  const float* W     = (const float*)d_in[1];
  const float* a     = (const float*)d_in[2];
  const float* adj   = (const float*)d_in[3];
  const int*   ei    = (const int*)d_in[4];
  const int*   src   = ei;
  const int*   dst   = ei + N_EDGES;
  float* out = (float*)d_out;

  // ---- workspace layout (all regions 16B-aligned) ----
  float* h    = (float*)d_ws;                        // 3.2M floats (12.8 MB)
  float* ssrc = h + (size_t)N_NODES * F_OUT;         // 50000
  float* sdst = ssrc + N_NODES;                      // 50000
  int*   deg    = (int*)(sdst + N_NODES);            // NP ints (zeroed)
  int*   cursor = deg + NP;                          // NP ints (zeroed)
  int*   offs   = cursor + NP;                       // NP+pad ints
  int*   bsum   = offs + NP;                         // 256 ints
  int*   boff   = bsum + 256;                        // 256 ints
  int2*  pairs  = (int2*)(boff + 256);               // 800000 int2 (6.4 MB)

  hipMemsetAsync(deg, 0, 2 * NP * sizeof(int), stream);  // deg + cursor

  k_hist   <<<N_EDGES / 256, 256, 0, stream>>>(src, deg);
  k_scan_a <<<NB, 256, 0, stream>>>(deg, offs, bsum);
  k_scan_b <<<1, 256, 0, stream>>>(bsum, boff);
  k_gemm_scores<<<N_NODES / 16, 256, 0, stream>>>(input, W, a, h, ssrc, sdst);
  k_scatter<<<N_EDGES / 256, 256, 0, stream>>>(src, dst, adj, ssrc, sdst,
                                               offs, boff, cursor, pairs);
  k_gather <<<N_NODES / 4, 256, 0, stream>>>(pairs, offs, boff, h, out);
}

// Round 4
// 260.694 us; speedup vs baseline: 1.0222x; 1.0222x over previous
//
#include <hip/hip_runtime.h>
#include <math.h>

#define N_NODES 50000
#define N_EDGES 800000
#define F_IN    128
#define F_OUT   64
#define ALPHA   0.2f

#define NP      50176              // N_NODES padded to 196*256
#define NB      196                // scan blocks

// ---------------------------------------------------------------------------
// K1: h = input @ W  (50000x128 @ 128x64), plus per-node attention scores
//     ssrc[i] = h[i,:] . a[0:64],  sdst[i] = h[i,:] . a[64:128]
// R3: 8 rows per wave (was 4). Diagnosis from profile: VALUBusy 26%,
// latency-stalled at FMA:ds_read = 4:1. Now 8:1 with 32 independent FMAs
// per LDS read group. 50000 = 6250 waves * 8 rows exact.
// ---------------------------------------------------------------------------
__global__ __launch_bounds__(256) void k_gemm_scores(
    const float* __restrict__ in, const float* __restrict__ W,
    const float* __restrict__ a, float* __restrict__ h,
    float* __restrict__ ssrc, float* __restrict__ sdst) {
  __shared__ float Wl[F_IN * F_OUT];   // 32 KB, row-major [k][j]
  __shared__ float al[2 * F_OUT];

  for (int i = threadIdx.x; i < F_IN * F_OUT; i += 256) Wl[i] = W[i];
  if (threadIdx.x < 2 * F_OUT) al[threadIdx.x] = a[threadIdx.x];
  __syncthreads();

  const int wave = threadIdx.x >> 6;
  const int lane = threadIdx.x & 63;
  const int wgrp = blockIdx.x * 4 + wave;         // 8-row group id
  if (wgrp >= N_NODES / 8) return;                // whole-wave skip (tail block)
  const int row0 = wgrp * 8;

  const float* rb = in + (size_t)row0 * F_IN;
  float acc[8] = {0.f, 0.f, 0.f, 0.f, 0.f, 0.f, 0.f, 0.f};

  #pragma unroll 4
  for (int k4 = 0; k4 < F_IN / 4; ++k4) {
    float4 iv[8];
    #pragma unroll
    for (int r = 0; r < 8; ++r)
      iv[r] = *reinterpret_cast<const float4*>(rb + (size_t)r * F_IN + k4 * 4);
    #pragma unroll
    for (int j = 0; j < 4; ++j) {
      const float w = Wl[(k4 * 4 + j) * F_OUT + lane];
      #pragma unroll
      for (int r = 0; r < 8; ++r)
        acc[r] += (&iv[r].x)[j] * w;
    }
  }

  #pragma unroll
  for (int r = 0; r < 8; ++r)
    h[(size_t)(row0 + r) * F_OUT + lane] = acc[r];

  const float as = al[lane], ad = al[F_OUT + lane];
  float ts[8], td[8];
  #pragma unroll
  for (int r = 0; r < 8; ++r) { ts[r] = acc[r] * as; td[r] = acc[r] * ad; }
  #pragma unroll
  for (int off = 32; off; off >>= 1) {
    #pragma unroll
    for (int r = 0; r < 8; ++r) {
      ts[r] += __shfl_xor(ts[r], off);
      td[r] += __shfl_xor(td[r], off);
    }
  }
  if (lane == 0) {
    #pragma unroll
    for (int r = 0; r < 8; ++r) {
      ssrc[row0 + r] = ts[r];
      sdst[row0 + r] = td[r];
    }
  }
}

// ---------------------------------------------------------------------------
// CSR build: histogram of src, 2-level exclusive scan, scatter {dst, ee}.
// ---------------------------------------------------------------------------
__global__ __launch_bounds__(256) void k_hist(const int* __restrict__ src,
                                              int* __restrict__ deg) {
  const int e = blockIdx.x * 256 + threadIdx.x;   // grid exact: 800000
  atomicAdd(&deg[src[e]], 1);
}

// per-block exclusive scan of 256 elements; bsum[b] = block total
__global__ __launch_bounds__(256) void k_scan_a(const int* __restrict__ deg,
                                                int* __restrict__ offs,
                                                int* __restrict__ bsum) {
  __shared__ int lds[256];
  const int i = blockIdx.x * 256 + threadIdx.x;   // deg zero-padded to NP
  const int v = deg[i];
  lds[threadIdx.x] = v;
  __syncthreads();
  #pragma unroll
  for (int off = 1; off < 256; off <<= 1) {
    int t = (threadIdx.x >= off) ? lds[threadIdx.x - off] : 0;
    __syncthreads();
    lds[threadIdx.x] += t;
    __syncthreads();
  }
  offs[i] = lds[threadIdx.x] - v;                 // exclusive within block
  if (threadIdx.x == 255) bsum[blockIdx.x] = lds[255];
}

// exclusive scan of the NB block sums (single block). bsum[NB..255] is
// POISON (0xAA) — guard the load.
__global__ __launch_bounds__(256) void k_scan_b(const int* __restrict__ bsum,
                                                int* __restrict__ boff) {
  __shared__ int lds[256];
  const int v = (threadIdx.x < NB) ? bsum[threadIdx.x] : 0;
  lds[threadIdx.x] = v;
  __syncthreads();
  #pragma unroll
  for (int off = 1; off < 256; off <<= 1) {
    int t = (threadIdx.x >= off) ? lds[threadIdx.x - off] : 0;
    __syncthreads();
    lds[threadIdx.x] += t;
    __syncthreads();
  }
  boff[threadIdx.x] = lds[threadIdx.x] - v;
}

// one thread per edge: compute ee once, place {dst, ee} in CSR slot of src
__global__ __launch_bounds__(256) void k_scatter(
    const int* __restrict__ src, const int* __restrict__ dst,
    const float* __restrict__ adj,
    const float* __restrict__ ssrc, const float* __restrict__ sdst,
    const int* __restrict__ offs, const int* __restrict__ boff,
    int* __restrict__ cursor, int2* __restrict__ pairs) {
  const int e = blockIdx.x * 256 + threadIdx.x;   // grid exact: 800000
  const int s = src[e];
  const int d = dst[e];
  const float sc = ssrc[s] + sdst[d];
  const float lr = sc > 0.f ? sc : ALPHA * sc;
  const float ee = expf(-lr) * adj[e];
  const int base = offs[s] + boff[s >> 8];
  const int pos  = base + atomicAdd(&cursor[s], 1);
  pairs[pos] = make_int2(d, __float_as_int(ee));
}

// ---------------------------------------------------------------------------
// K4: per-node gather + divide + ELU (fused epilogue). Wave per node,
// lane = feature. R3: 4-edge unroll — 4 pair loads + 4 h-row loads in
// flight per wave (1 KB); 32 waves/CU -> 32 KB/CU in flight, safely
// BW-bound against L2/L3 instead of latency-bound.
// ---------------------------------------------------------------------------
__global__ __launch_bounds__(256) void k_gather(
    const int2* __restrict__ pairs, const int* __restrict__ offs,
    const int* __restrict__ boff, const float* __restrict__ h,
    float* __restrict__ out) {
  const int wave = threadIdx.x >> 6;
  const int lane = threadIdx.x & 63;
  const int node = blockIdx.x * 4 + wave;         // grid exact: 12500

  const int o0 = offs[node] + boff[node >> 8];
  const int o1 = offs[node + 1] + boff[(node + 1) >> 8];

  float acc = 0.f, rs = 0.f;
  int j = o0;
  for (; j + 3 < o1; j += 4) {
    const int2 p0 = pairs[j];
    const int2 p1 = pairs[j + 1];
    const int2 p2 = pairs[j + 2];
    const int2 p3 = pairs[j + 3];
    const float h0 = h[(size_t)p0.x * F_OUT + lane];
    const float h1 = h[(size_t)p1.x * F_OUT + lane];
    const float h2 = h[(size_t)p2.x * F_OUT + lane];
    const float h3 = h[(size_t)p3.x * F_OUT + lane];
    const float e0 = __int_as_float(p0.y);
    const float e1 = __int_as_float(p1.y);
    const float e2 = __int_as_float(p2.y);
    const float e3 = __int_as_float(p3.y);
    acc += e0 * h0; rs += e0;
    acc += e1 * h1; rs += e1;
    acc += e2 * h2; rs += e2;
    acc += e3 * h3; rs += e3;
  }
  for (; j < o1; ++j) {
    const int2 p = pairs[j];
    const float ee = __int_as_float(p.y);
    acc += ee * h[(size_t)p.x * F_OUT + lane];
    rs  += ee;
  }

  float v = acc / rs;                             // deg==0 -> NaN, matches ref
  v = v > 0.f ? v : expm1f(v);
  out[(size_t)node * F_OUT + lane] = v;
}

extern "C" void kernel_launch(void* const* d_in, const int* in_sizes, int n_in,
                              void* d_out, int out_size, void* d_ws, size_t ws_size,
                              hipStream_t stream) {
  const float* input = (const float*)d_in[0];
  const float* W     = (const float*)d_in[1];
  const float* a     = (const float*)d_in[2];
  const float* adj   = (const float*)d_in[3];
  const int*   ei    = (const int*)d_in[4];
  const int*   src   = ei;
  const int*   dst   = ei + N_EDGES;
  float* out = (float*)d_out;

  // ---- workspace layout (all regions 16B-aligned) ----
  float* h    = (float*)d_ws;                        // 3.2M floats (12.8 MB)
  float* ssrc = h + (size_t)N_NODES * F_OUT;         // 50000
  float* sdst = ssrc + N_NODES;                      // 50000
  int*   deg    = (int*)(sdst + N_NODES);            // NP ints (zeroed)
  int*   cursor = deg + NP;                          // NP ints (zeroed)
  int*   offs   = cursor + NP;                       // NP ints
  int*   bsum   = offs + NP;                         // 256 ints
  int*   boff   = bsum + 256;                        // 256 ints
  int2*  pairs  = (int2*)(boff + 256);               // 800000 int2 (6.4 MB)

  hipMemsetAsync(deg, 0, 2 * NP * sizeof(int), stream);  // deg + cursor

  k_hist   <<<N_EDGES / 256, 256, 0, stream>>>(src, deg);
  k_scan_a <<<NB, 256, 0, stream>>>(deg, offs, bsum);
  k_scan_b <<<1, 256, 0, stream>>>(bsum, boff);
  k_gemm_scores<<<(N_NODES / 8 + 3) / 4, 256, 0, stream>>>(input, W, a, h, ssrc, sdst);
  k_scatter<<<N_EDGES / 256, 256, 0, stream>>>(src, dst, adj, ssrc, sdst,
                                               offs, boff, cursor, pairs);
  k_gather <<<N_NODES / 4, 256, 0, stream>>>(pairs, offs, boff, h, out);
}